// Round 15
// baseline (397.895 us; speedup 1.0000x reference)
//
#include <hip/hip_runtime.h>

typedef __bf16 bf16x8 __attribute__((ext_vector_type(8)));
typedef __bf16 bf16x4 __attribute__((ext_vector_type(4)));
typedef float f32x4 __attribute__((ext_vector_type(4)));
typedef unsigned int u32x4v __attribute__((ext_vector_type(4)));

#define LN_EPS 1e-5f

// async global->LDS, 16B per lane (HW: wave-uniform LDS base + lane*16)
__device__ __forceinline__ void gl2lds16(const void* g, void* l) {
  __builtin_amdgcn_global_load_lds(
      (const __attribute__((address_space(1))) unsigned int*)g,
      (__attribute__((address_space(3))) unsigned int*)l, 16, 0, 0);
}

// pipeline barrier: wait only the KEEP newest in-flight loads (they stay
// outstanding across the barrier), then s_barrier. KEEP=0 == full drain.
template <int KEEP>
__device__ __forceinline__ void pipe_barrier() {
  if constexpr (KEEP == 0)
    __asm__ __volatile__("s_waitcnt vmcnt(0) lgkmcnt(0)\n\ts_barrier" ::: "memory");
  else if constexpr (KEEP == 2)
    __asm__ __volatile__("s_waitcnt vmcnt(2) lgkmcnt(0)\n\ts_barrier" ::: "memory");
  else if constexpr (KEEP == 3)
    __asm__ __volatile__("s_waitcnt vmcnt(3) lgkmcnt(0)\n\ts_barrier" ::: "memory");
  else if constexpr (KEEP == 4)
    __asm__ __volatile__("s_waitcnt vmcnt(4) lgkmcnt(0)\n\ts_barrier" ::: "memory");
  else if constexpr (KEEP == 6)
    __asm__ __volatile__("s_waitcnt vmcnt(6) lgkmcnt(0)\n\ts_barrier" ::: "memory");
}

// pack two f32 -> one u32 of 2 bf16 (RNE), same numerics as (__bf16) casts
__device__ __forceinline__ unsigned cvt_pk_bf16(float lo, float hi) {
  unsigned r;
  asm("v_cvt_pk_bf16_f32 %0, %1, %2" : "=v"(r) : "v"(lo), "v"(hi));
  return r;
}
// swap 32-lane halves: a'=[A0,B0], b'=[A1,B1]
__device__ __forceinline__ void plane32_swap(unsigned& a, unsigned& b) {
  asm("v_permlane32_swap_b32 %0, %1" : "+v"(a), "+v"(b));
}
// swap odd 16-rows of a with even 16-rows of b
__device__ __forceinline__ void plane16_swap(unsigned& a, unsigned& b) {
  asm("v_permlane16_swap_b32 %0, %1" : "+v"(a), "+v"(b));
}

// -------- merged weight transpose + downcast: 4 matrices, one dispatch --------
// ranges over linear blockIdx.x; per range: in f32 [R][C] -> out bf16 [C][R].
//   [0,1728)    qkv  R=768  C=2304  (72 x-tiles)
//   [1728,2304) proj R=768  C=768   (24)
//   [2304,4608) fc1  R=768  C=3072  (96)
//   [4608,6912) fc2  R=3072 C=768   (24)
__global__ __launch_bounds__(256) void transpose_all(const float* __restrict__ qkvw,
                                                     __bf16* __restrict__ o_qkv,
                                                     const float* __restrict__ projw,
                                                     __bf16* __restrict__ o_proj,
                                                     const float* __restrict__ fc1w,
                                                     __bf16* __restrict__ o_fc1,
                                                     const float* __restrict__ fc2w,
                                                     __bf16* __restrict__ o_fc2) {
  const float* in;
  __bf16* out;
  int R, C, bx, by;
  int l = blockIdx.x;
  if (l < 1728) {
    in = qkvw; out = o_qkv; R = 768; C = 2304; bx = l % 72; by = l / 72;
  } else if (l < 2304) {
    l -= 1728; in = projw; out = o_proj; R = 768; C = 768; bx = l % 24; by = l / 24;
  } else if (l < 4608) {
    l -= 2304; in = fc1w; out = o_fc1; R = 768; C = 3072; bx = l % 96; by = l / 96;
  } else {
    l -= 4608; in = fc2w; out = o_fc2; R = 3072; C = 768; bx = l % 24; by = l / 24;
  }
  __shared__ __bf16 t[32][33];
  int tx = threadIdx.x & 31, ty = threadIdx.x >> 5;  // 32x8
  int c = bx * 32 + tx;
  for (int j = 0; j < 4; j++) {
    int r = by * 32 + ty + j * 8;
    t[ty + j * 8][tx] = (__bf16)in[(size_t)r * C + c];
  }
  __syncthreads();
  int r2 = by * 32 + tx;
  for (int j = 0; j < 4; j++) {
    int c2 = bx * 32 + ty + j * 8;
    out[(size_t)c2 * R + r2] = t[tx][ty + j * 8];
  }
}

// -------- layernorm over 768: f32 in -> bf16 out, one block per row --------
__global__ __launch_bounds__(256) void ln_kernel(const float* __restrict__ x,
                                                 const float* __restrict__ g,
                                                 const float* __restrict__ bta,
                                                 __bf16* __restrict__ out) {
  int row = blockIdx.x;
  size_t base = (size_t)row * 768;
  int t = threadIdx.x;
  float v[3];
  float s = 0.f, s2 = 0.f;
  for (int k = 0; k < 3; k++) {
    float f = x[base + t + k * 256];
    v[k] = f;
    s += f;
    s2 += f * f;
  }
  for (int m = 1; m < 64; m <<= 1) {
    s += __shfl_xor(s, m, 64);
    s2 += __shfl_xor(s2, m, 64);
  }
  __shared__ float sm[4][2];
  int wid = t >> 6, lane = t & 63;
  if (lane == 0) { sm[wid][0] = s; sm[wid][1] = s2; }
  __syncthreads();
  s = sm[0][0] + sm[1][0] + sm[2][0] + sm[3][0];
  s2 = sm[0][1] + sm[1][1] + sm[2][1] + sm[3][1];
  float mu = s * (1.f / 768.f);
  float var = s2 * (1.f / 768.f) - mu * mu;
  float rstd = rsqrtf(var + LN_EPS);
  for (int k = 0; k < 3; k++) {
    int c = t + k * 256;
    out[base + c] = (__bf16)((v[k] - mu) * rstd * g[c] + bta[c]);
  }
}

// -------- pipelined MFMA GEMM (BK=32): RING-buffer glds, graded vmcnt barrier --
// C[M,N] = A[M,K] @ BT[N,K]^T + bias. Tile MT x NT (2x2 waves).
// LDS layout: paired-row [rows/2][64] (128B rows), 8x16B logical slots
// (bit2 = m-parity, bits1:0 = k-chunk), XOR-swizzled by (lds_row & 7).
// Source pre-applies the involution, glds dest stays linear, reads un-apply ->
// measured-zero bank conflicts (R7..R13).
// RING=3: stage 2 ahead. RING=4: stage 3 ahead (R11: fc2 73.2->70.7).
// Tail KEEP grading: KEEP = min(RING-2, T-1-it)*S.
// 64x64 tile + WPB=6 (thin-N GEMMs): 6 blocks/CU resident -> 2x wave
// concurrency to hide the ds_read->MFMA chain (R14 experiment).
// No setprio (lockstep waves; m190). EPI 1: gelu ; 2: +res f32 ; 3: qkv+V^T
template <int MT, int NT, int EPI, bool SWAP, int WPB, int RING>
__global__ __launch_bounds__(256, WPB)
void gemm_pl(const __bf16* __restrict__ A, const __bf16* __restrict__ BT,
             const float* __restrict__ bias, const float* __restrict__ res,
             void* __restrict__ outv, __bf16* __restrict__ vtb,
             int M, int N, int K,
             const float* __restrict__ c0p, const float* __restrict__ c1p,
             const float* __restrict__ c2p) {
  __shared__ __bf16 As[RING][MT / 2][64];
  __shared__ __bf16 Bs[RING][NT / 2][64];
  constexpr int IW = MT / 32, JW = NT / 32;
  constexpr int S = MT / 64 + NT / 64;  // glds per wave per stage
  const int tid = threadIdx.x, lane = tid & 63, wid = tid >> 6;
  const int wr = wid >> 1, wc = wid & 1;
  const int mr = lane & 15, quad = lane >> 4;
  const int bx = SWAP ? blockIdx.y : blockIdx.x;
  const int by = SWAP ? blockIdx.x : blockIdx.y;
  const int m0 = by * MT, n0 = bx * NT;

  // staging lane geometry: dest slot (lane&7) holds logical slot sl
  const int sl = (lane & 7) ^ (lane >> 3);
  const int srow2 = 2 * (lane >> 3) + (sl >> 2);  // m-offset within 16-row group
  const int skc = (sl & 3) * 8;                   // k-offset (bf16)
  // read geometry: logical slot (m-parity, kchunk=quad) -> swizzled slot
  const int rrow = mr >> 1;
  const int rcol = ((((mr & 1) << 2) | quad) ^ rrow) * 8;

  f32x4 acc[IW][JW] = {};

  // hoisted staging pointers: per-lane global src, per-lane LDS dst
  const size_t gK = (size_t)16 * K;
  const __bf16* aS = A + (size_t)(m0 + wid * (MT / 4) + srow2) * K + skc;
  const __bf16* bS = BT + (size_t)(n0 + wid * (NT / 4) + srow2) * K + skc;
  __bf16* dA0 = &As[0][wid * (MT / 8)][0] + lane * 8;  // linear: lane*16B
  __bf16* dB0 = &Bs[0][wid * (NT / 8)][0] + lane * 8;

  auto stage = [&](int k0, int buf) {
    __bf16* da = dA0 + buf * (MT * 32);
    __bf16* db = dB0 + buf * (NT * 32);
    for (int g = 0; g < MT / 64; g++) gl2lds16(aS + k0 + g * gK, da + g * 512);
    for (int g = 0; g < NT / 64; g++) gl2lds16(bS + k0 + g * gK, db + g * 512);
  };

  const int T = K / 32;
  for (int r = 0; r < RING - 1; r++) stage(r * 32, r);
  for (int it = 0; it < T; it++) {
    // drain stage(it); keep min(RING-2, T-1-it) newer stages in flight
    const int rem = T - 1 - it;
    if (rem >= RING - 2) {
      pipe_barrier<(RING - 2) * S>();
    } else if constexpr (RING == 4) {
      if (rem == 1) pipe_barrier<S>(); else pipe_barrier<0>();
    } else {
      pipe_barrier<0>();
    }
    if (it + RING - 1 < T) stage((it + RING - 1) * 32, (it + RING - 1) % RING);
    const int pb = it % RING;
    bf16x8 af[IW], bfr[JW];
    for (int i = 0; i < IW; i++)
      af[i] = *(bf16x8*)&As[pb][wr * (MT / 4) + i * 8 + rrow][rcol];
    for (int j = 0; j < JW; j++)
      bfr[j] = *(bf16x8*)&Bs[pb][wc * (NT / 4) + j * 8 + rrow][rcol];
    for (int i = 0; i < IW; i++)
      for (int j = 0; j < JW; j++)
        acc[i][j] = __builtin_amdgcn_mfma_f32_16x16x32_bf16(af[i], bfr[j], acc[i][j], 0, 0, 0);
  }

  float ga = 0.f, gb = 0.f, gc = 0.f;
  if (EPI == 1) { ga = *c0p; gb = *c1p; gc = *c2p; }

  for (int i = 0; i < IW; i++) {
    for (int j = 0; j < JW; j++) {
      int col = n0 + wc * (NT / 2) + j * 16 + mr;
      float bv = bias[col];
      int row0 = m0 + wr * (MT / 2) + i * 16 + quad * 4;
      if (EPI == 3 && col >= 1536) {
        // V-part: write directly into V^T[(b*12+h)*64+d][token], 4 tokens/lane
        int hh = (col >> 6) - 24, dd = col & 63;
        bf16x4 pk;
        for (int r = 0; r < 4; r++) pk[r] = (__bf16)(acc[i][j][r] + bv);
        *(bf16x4*)&vtb[(((size_t)(row0 >> 11) * 12 + hh) * 64 + dd) * 2048 +
                       (row0 & 2047)] = pk;
      } else {
        for (int r = 0; r < 4; r++) {
          size_t idx = (size_t)(row0 + r) * N + col;
          float c = acc[i][j][r] + bv;
          if (EPI == 1) {
            float u = (ga * c + gb) * c + gc;
            ((__bf16*)outv)[idx] = (__bf16)u;
          } else if (EPI == 2) {
            ((float*)outv)[idx] = c + res[idx];
          } else {
            ((__bf16*)outv)[idx] = (__bf16)c;
          }
        }
      }
    }
  }
}

// -------- flash-style polynomial attention --------
// grid(48, 16): x = b*12+h (same-head q-tiles share an XCD), y = q-tile.
// P kept fully in registers (cvt_pk + permlane, T12). Row-sum via
// ones-vector MFMA (pf as B-operand -> C[.][q=mr] = rowsum) (R8/R10+-verified).
// setprio kept here: independent per-block waves (phase-diverse) — T5 pays.
__global__ __launch_bounds__(256, 3) void attn_poly(const __bf16* __restrict__ qkv,
                                                    const __bf16* __restrict__ vt,
                                                    __bf16* __restrict__ outp,
                                                    const float* __restrict__ ap,
                                                    const float* __restrict__ bp,
                                                    const float* __restrict__ cp) {
  __shared__ __bf16 Kb[2][64][64];   // 16,384 B (unpadded, swizzled chunks)
  __shared__ __bf16 Vb[2][64][64];   // 16,384 B

  const int tid = threadIdx.x, lane = tid & 63, wid = tid >> 6;
  const int mr = lane & 15, quad = lane >> 4;
  const int bh = blockIdx.x;
  const int h = bh % 12, b = bh / 12;
  const int q0 = blockIdx.y * 128;
  const size_t baseQ = ((size_t)b * 2048) * 2304 + h * 64;

  const int swzsrc = (((lane & 7) ^ ((lane >> 3) & 7)) * 8);
  const int srow8 = lane >> 3;
  const int colS0 = ((quad ^ (mr & 7)) * 8);
  const int colS1 = (((4 + quad) ^ (mr & 7)) * 8);

  bf16x8 qf[2][2];
  for (int i = 0; i < 2; i++)
    for (int s = 0; s < 2; s++)
      qf[i][s] = *(const bf16x8*)&qkv[baseQ + (size_t)(q0 + wid * 32 + i * 16 + mr) * 2304 +
                                      s * 32 + quad * 8];

  const float a2 = (*ap) * 0.015625f, b2 = (*bp) * 0.125f, cc = *cp;
  f32x4 o_acc[2][4] = {};
  f32x4 osum[2] = {};                // MFMA row-sum accumulators
  const f32x4 z4 = {0.f, 0.f, 0.f, 0.f};  // persistent MFMA C-zero
  const bf16x8 ones = {(__bf16)1.f, (__bf16)1.f, (__bf16)1.f, (__bf16)1.f,
                       (__bf16)1.f, (__bf16)1.f, (__bf16)1.f, (__bf16)1.f};

  // staging pointers: per-lane global src advanced by constant strides
  const __bf16* kp = qkv + baseQ + 768 + (size_t)(wid * 16 + srow8) * 2304 + swzsrc;
  const __bf16* vp = vt + ((size_t)bh * 64 + wid * 16 + srow8) * 2048 + swzsrc;
  __bf16* kd0 = &Kb[0][wid * 16 + srow8][(lane & 7) * 8];
  __bf16* vd0 = &Vb[0][wid * 16 + srow8][(lane & 7) * 8];

  auto stage = [&](const __bf16* kpp, const __bf16* vpp, int pbuf) {
    __bf16* kd = kd0 + pbuf * 4096;
    __bf16* vd = vd0 + pbuf * 4096;
    gl2lds16(kpp, kd);
    gl2lds16(kpp + 8 * 2304, kd + 512);
    gl2lds16(vpp, vd);
    gl2lds16(vpp + 8 * 2048, vd + 512);
  };

  stage(kp, vp, 0);
  const __bf16* kpn = kp + 64 * 2304;
  const __bf16* vpn = vp + 64;
  int pb = 0;
  for (int kt = 0; kt < 32; kt++) {
    __syncthreads();
    if (kt < 31) { stage(kpn, vpn, pb ^ 1); kpn += 64 * 2304; vpn += 64; }
    const __bf16* kb = &Kb[pb][0][0];
    const __bf16* vb = &Vb[pb][0][0];

    // QK^T (swapped: A=K rows, B=Q rows) -> lane(mr,quad) holds
    // S[q=mr][k = j*16 + quad*4 + r] in sacc[i][j][r]
    f32x4 sacc[2][4];
    __builtin_amdgcn_s_setprio(1);
    for (int j = 0; j < 4; j++) {
      bf16x8 kf0 = *(bf16x8*)(kb + (j * 16 + mr) * 64 + colS0);
      bf16x8 kf1 = *(bf16x8*)(kb + (j * 16 + mr) * 64 + colS1);
      for (int i = 0; i < 2; i++) {
        sacc[i][j] = __builtin_amdgcn_mfma_f32_16x16x32_bf16(kf0, qf[i][0], z4, 0, 0, 0);
        sacc[i][j] = __builtin_amdgcn_mfma_f32_16x16x32_bf16(kf1, qf[i][1], sacc[i][j], 0, 0, 0);
      }
    }
    __builtin_amdgcn_s_setprio(0);

    // activation + in-register P redistribution into PV A-fragments:
    // target lane(mr,quad) needs P[q=mr][k = s*32 + quad*8 + e], e=0..7.
    bf16x8 pf[2][2];
    for (int i = 0; i < 2; i++) {
      unsigned w0[4], w1[4];
      for (int j = 0; j < 4; j++) {
        f32x4 S = sacc[i][j];
        f32x4 p = (a2 * S + b2) * S + cc;
        p[0] = fmaxf(p[0], 1e-6f); p[1] = fmaxf(p[1], 1e-6f);
        p[2] = fmaxf(p[2], 1e-6f); p[3] = fmaxf(p[3], 1e-6f);
        w0[j] = cvt_pk_bf16(p[0], p[1]);
        w1[j] = cvt_pk_bf16(p[2], p[3]);
      }
      for (int s = 0; s < 2; s++) {
        unsigned a0 = w0[2 * s], b0 = w0[2 * s + 1];
        unsigned a1 = w1[2 * s], b1 = w1[2 * s + 1];
        plane32_swap(a0, b0); plane16_swap(a0, b0);
        plane32_swap(a1, b1); plane16_swap(a1, b1);
        u32x4v t = {a0, a1, b0, b1};
        pf[i][s] = __builtin_bit_cast(bf16x8, t);
      }
    }

    // PV: o[q][d] += P[q][k] * V^T[d][k] ; row-sum via ones-MFMA
    __builtin_amdgcn_s_setprio(1);
    for (int s = 0; s < 2; s++) {
      for (int i = 0; i < 2; i++)
        osum[i] = __builtin_amdgcn_mfma_f32_16x16x32_bf16(ones, pf[i][s], osum[i], 0, 0, 0);
      for (int dt = 0; dt < 4; dt++) {
        bf16x8 vf = *(bf16x8*)(vb + (dt * 16 + mr) * 64 + (s ? colS1 : colS0));
        for (int i = 0; i < 2; i++)
          o_acc[i][dt] = __builtin_amdgcn_mfma_f32_16x16x32_bf16(pf[i][s], vf, o_acc[i][dt], 0, 0, 0);
      }
    }
    __builtin_amdgcn_s_setprio(0);
    pb ^= 1;
  }

  size_t baseO = ((size_t)b * 2048) * 768 + h * 64;
  for (int i = 0; i < 2; i++) {
    float l_acc = osum[i][0];  // rowsum(q=mr), replicated across regs
    float inv[4];
    for (int r = 0; r < 4; r++)
      inv[r] = 1.0f / (__shfl(l_acc, quad * 4 + r, 64) + 1e-8f);
    for (int dt = 0; dt < 4; dt++) {
      int q = q0 + wid * 32 + i * 16 + quad * 4;
      for (int r = 0; r < 4; r++)
        outp[baseO + (size_t)(q + r) * 768 + dt * 16 + mr] =
            (__bf16)(o_acc[i][dt][r] * inv[r]);
    }
  }
}

extern "C" void kernel_launch(void* const* d_in, const int* in_sizes, int n_in,
                              void* d_out, int out_size, void* d_ws, size_t ws_size,
                              hipStream_t stream) {
  const float* x     = (const float*)d_in[0];
  const float* ln1g  = (const float*)d_in[1];
  const float* ln1b  = (const float*)d_in[2];
  const float* ln2g  = (const float*)d_in[3];
  const float* ln2b  = (const float*)d_in[4];
  const float* qkvw  = (const float*)d_in[5];
  const float* qkvb  = (const float*)d_in[6];
  const float* projw = (const float*)d_in[7];
  const float* projb = (const float*)d_in[8];
  const float* fc1w  = (const float*)d_in[9];
  const float* fc1b  = (const float*)d_in[10];
  const float* fc2w  = (const float*)d_in[11];
  const float* fc2b  = (const float*)d_in[12];
  const float* attna = (const float*)d_in[13];
  const float* attnb = (const float*)d_in[14];
  const float* attnc = (const float*)d_in[15];
  const float* gelua = (const float*)d_in[16];
  const float* gelub = (const float*)d_in[17];
  const float* geluc = (const float*)d_in[18];

  char* ws = (char*)d_ws;
  __bf16* wT_qkv  = (__bf16*)(ws);             // [2304][768]  3,538,944 B
  __bf16* wT_proj = (__bf16*)(ws + 3538944);   // [768][768]   1,179,648 B
  __bf16* wT_fc1  = (__bf16*)(ws + 4718592);   // [3072][768]  4,718,592 B
  __bf16* wT_fc2  = (__bf16*)(ws + 9437184);   // [768][3072]  4,718,592 B
  __bf16* h       = (__bf16*)(ws + 14155776);  // [8192][768]  bf16 12,582,912 B
  float*  x1      = (float*)(ws + 26738688);   // [8192][768]  f32  25,165,824 B
  __bf16* qkvbuf  = (__bf16*)(ws + 51904512);  // [8192][2304] bf16 (dead after attn)
  __bf16* u       = (__bf16*)(ws + 51904512);  // [8192][3072] bf16 (overlaps qkv)
  __bf16* vtbuf   = (__bf16*)(ws + 89653248);  // [3072][2048] bf16 (live qkv->attn only)
  float*  outp    = (float*)d_out;

  // all 4 weight transposes in one dispatch (6912 tiles)
  transpose_all<<<6912, 256, 0, stream>>>(qkvw, wT_qkv, projw, wT_proj,
                                          fc1w, wT_fc1, fc2w, wT_fc2);

  ln_kernel<<<8192, 256, 0, stream>>>(x, ln1g, ln1b, h);
  // qkv GEMM with fused V^T epilogue (writes Q|K to qkvbuf, V^T to vtbuf)
  gemm_pl<128, 128, 3, false, 3, 3><<<dim3(18, 64), 256, 0, stream>>>(
      h, wT_qkv, qkvb, nullptr, qkvbuf, vtbuf, 8192, 2304, 768, nullptr, nullptr, nullptr);
  // grid: x = b*12+h (XCD-local K/V reuse), y = q-tile
  attn_poly<<<dim3(48, 16), 256, 0, stream>>>(qkvbuf, vtbuf, h, attna, attnb, attnc);
  // proj (+x residual) -> x1 f32 ; 64x64 tile, 6 blocks/CU (2x concurrency)
  gemm_pl<64, 64, 2, true, 6, 3><<<dim3(128, 12), 256, 0, stream>>>(
      h, wT_proj, projb, x, x1, nullptr, 8192, 768, 768, nullptr, nullptr, nullptr);
  ln_kernel<<<8192, 256, 0, stream>>>(x1, ln2g, ln2b, h);
  // fc1 + gelu: 128x128 (R7-proven), RING=3
  gemm_pl<128, 128, 1, false, 3, 3><<<dim3(24, 64), 256, 0, stream>>>(
      h, wT_fc1, fc1b, nullptr, u, nullptr, 8192, 3072, 768, gelua, gelub, geluc);
  // fc2 (+x1 residual) -> out f32 ; 64x64 tile, 6 blocks/CU
  gemm_pl<64, 64, 2, true, 6, 3><<<dim3(128, 12), 256, 0, stream>>>(
      u, wT_fc2, fc2b, x1, outp, nullptr, 8192, 768, 3072, nullptr, nullptr, nullptr);
}

// Round 16
// 386.545 us; speedup vs baseline: 1.0294x; 1.0294x over previous
//
#include <hip/hip_runtime.h>

typedef __bf16 bf16x8 __attribute__((ext_vector_type(8)));
typedef __bf16 bf16x4 __attribute__((ext_vector_type(4)));
typedef float f32x4 __attribute__((ext_vector_type(4)));
typedef unsigned int u32x4v __attribute__((ext_vector_type(4)));

#define LN_EPS 1e-5f

// async global->LDS, 16B per lane (HW: wave-uniform LDS base + lane*16)
__device__ __forceinline__ void gl2lds16(const void* g, void* l) {
  __builtin_amdgcn_global_load_lds(
      (const __attribute__((address_space(1))) unsigned int*)g,
      (__attribute__((address_space(3))) unsigned int*)l, 16, 0, 0);
}

// pipeline barrier: wait only the KEEP newest in-flight loads (they stay
// outstanding across the barrier), then s_barrier. KEEP=0 == full drain.
template <int KEEP>
__device__ __forceinline__ void pipe_barrier() {
  if constexpr (KEEP == 0)
    __asm__ __volatile__("s_waitcnt vmcnt(0) lgkmcnt(0)\n\ts_barrier" ::: "memory");
  else if constexpr (KEEP == 2)
    __asm__ __volatile__("s_waitcnt vmcnt(2) lgkmcnt(0)\n\ts_barrier" ::: "memory");
  else if constexpr (KEEP == 3)
    __asm__ __volatile__("s_waitcnt vmcnt(3) lgkmcnt(0)\n\ts_barrier" ::: "memory");
  else if constexpr (KEEP == 4)
    __asm__ __volatile__("s_waitcnt vmcnt(4) lgkmcnt(0)\n\ts_barrier" ::: "memory");
  else if constexpr (KEEP == 6)
    __asm__ __volatile__("s_waitcnt vmcnt(6) lgkmcnt(0)\n\ts_barrier" ::: "memory");
}

// pack two f32 -> one u32 of 2 bf16 (RNE), same numerics as (__bf16) casts
__device__ __forceinline__ unsigned cvt_pk_bf16(float lo, float hi) {
  unsigned r;
  asm("v_cvt_pk_bf16_f32 %0, %1, %2" : "=v"(r) : "v"(lo), "v"(hi));
  return r;
}
// swap 32-lane halves: a'=[A0,B0], b'=[A1,B1]
__device__ __forceinline__ void plane32_swap(unsigned& a, unsigned& b) {
  asm("v_permlane32_swap_b32 %0, %1" : "+v"(a), "+v"(b));
}
// swap odd 16-rows of a with even 16-rows of b
__device__ __forceinline__ void plane16_swap(unsigned& a, unsigned& b) {
  asm("v_permlane16_swap_b32 %0, %1" : "+v"(a), "+v"(b));
}

// -------- merged weight transpose + downcast: 4 matrices, one dispatch --------
// ranges over linear blockIdx.x; per range: in f32 [R][C] -> out bf16 [C][R].
//   [0,1728)    qkv  R=768  C=2304  (72 x-tiles)
//   [1728,2304) proj R=768  C=768   (24)
//   [2304,4608) fc1  R=768  C=3072  (96)
//   [4608,6912) fc2  R=3072 C=768   (24)
__global__ __launch_bounds__(256) void transpose_all(const float* __restrict__ qkvw,
                                                     __bf16* __restrict__ o_qkv,
                                                     const float* __restrict__ projw,
                                                     __bf16* __restrict__ o_proj,
                                                     const float* __restrict__ fc1w,
                                                     __bf16* __restrict__ o_fc1,
                                                     const float* __restrict__ fc2w,
                                                     __bf16* __restrict__ o_fc2) {
  const float* in;
  __bf16* out;
  int R, C, bx, by;
  int l = blockIdx.x;
  if (l < 1728) {
    in = qkvw; out = o_qkv; R = 768; C = 2304; bx = l % 72; by = l / 72;
  } else if (l < 2304) {
    l -= 1728; in = projw; out = o_proj; R = 768; C = 768; bx = l % 24; by = l / 24;
  } else if (l < 4608) {
    l -= 2304; in = fc1w; out = o_fc1; R = 768; C = 3072; bx = l % 96; by = l / 96;
  } else {
    l -= 4608; in = fc2w; out = o_fc2; R = 3072; C = 768; bx = l % 24; by = l / 24;
  }
  __shared__ __bf16 t[32][33];
  int tx = threadIdx.x & 31, ty = threadIdx.x >> 5;  // 32x8
  int c = bx * 32 + tx;
  for (int j = 0; j < 4; j++) {
    int r = by * 32 + ty + j * 8;
    t[ty + j * 8][tx] = (__bf16)in[(size_t)r * C + c];
  }
  __syncthreads();
  int r2 = by * 32 + tx;
  for (int j = 0; j < 4; j++) {
    int c2 = bx * 32 + ty + j * 8;
    out[(size_t)c2 * R + r2] = t[tx][ty + j * 8];
  }
}

// -------- layernorm over 768: f32 in -> bf16 out, one block per row --------
__global__ __launch_bounds__(256) void ln_kernel(const float* __restrict__ x,
                                                 const float* __restrict__ g,
                                                 const float* __restrict__ bta,
                                                 __bf16* __restrict__ out) {
  int row = blockIdx.x;
  size_t base = (size_t)row * 768;
  int t = threadIdx.x;
  float v[3];
  float s = 0.f, s2 = 0.f;
  for (int k = 0; k < 3; k++) {
    float f = x[base + t + k * 256];
    v[k] = f;
    s += f;
    s2 += f * f;
  }
  for (int m = 1; m < 64; m <<= 1) {
    s += __shfl_xor(s, m, 64);
    s2 += __shfl_xor(s2, m, 64);
  }
  __shared__ float sm[4][2];
  int wid = t >> 6, lane = t & 63;
  if (lane == 0) { sm[wid][0] = s; sm[wid][1] = s2; }
  __syncthreads();
  s = sm[0][0] + sm[1][0] + sm[2][0] + sm[3][0];
  s2 = sm[0][1] + sm[1][1] + sm[2][1] + sm[3][1];
  float mu = s * (1.f / 768.f);
  float var = s2 * (1.f / 768.f) - mu * mu;
  float rstd = rsqrtf(var + LN_EPS);
  for (int k = 0; k < 3; k++) {
    int c = t + k * 256;
    out[base + c] = (__bf16)((v[k] - mu) * rstd * g[c] + bta[c]);
  }
}

// -------- pipelined MFMA GEMM (BK=32): RING-buffer glds, graded vmcnt barrier --
// C[M,N] = A[M,K] @ BT[N,K]^T + bias. Tile MT x NT (2x2 waves).
// LDS layout: paired-row [rows/2][64] (128B rows), 8x16B logical slots
// (bit2 = m-parity, bits1:0 = k-chunk), XOR-swizzled by (lds_row & 7).
// Source pre-applies the involution, glds dest stays linear, reads un-apply ->
// measured-zero bank conflicts (R7..R13).
// RING=3: stage 2 ahead. RING=4: stage 3 ahead (R11: fc2 73.2->70.7).
// Tail KEEP grading: KEEP = min(RING-2, T-1-it)*S.
// Thin-GEMM tile-space fully mapped: 64x128+RING=4 is the optimum
// (R4: 2xBK loses occupancy; R6: 128^2 starves grid; R15: 64x64 is
// LDS-issue-bound, +33% traffic regresses despite 2x occupancy).
// No setprio (lockstep waves; m190). EPI 1: gelu ; 2: +res f32 ; 3: qkv+V^T
template <int MT, int NT, int EPI, bool SWAP, int WPB, int RING>
__global__ __launch_bounds__(256, WPB)
void gemm_pl(const __bf16* __restrict__ A, const __bf16* __restrict__ BT,
             const float* __restrict__ bias, const float* __restrict__ res,
             void* __restrict__ outv, __bf16* __restrict__ vtb,
             int M, int N, int K,
             const float* __restrict__ c0p, const float* __restrict__ c1p,
             const float* __restrict__ c2p) {
  __shared__ __bf16 As[RING][MT / 2][64];
  __shared__ __bf16 Bs[RING][NT / 2][64];
  constexpr int IW = MT / 32, JW = NT / 32;
  constexpr int S = MT / 64 + NT / 64;  // glds per wave per stage
  const int tid = threadIdx.x, lane = tid & 63, wid = tid >> 6;
  const int wr = wid >> 1, wc = wid & 1;
  const int mr = lane & 15, quad = lane >> 4;
  const int bx = SWAP ? blockIdx.y : blockIdx.x;
  const int by = SWAP ? blockIdx.x : blockIdx.y;
  const int m0 = by * MT, n0 = bx * NT;

  // staging lane geometry: dest slot (lane&7) holds logical slot sl
  const int sl = (lane & 7) ^ (lane >> 3);
  const int srow2 = 2 * (lane >> 3) + (sl >> 2);  // m-offset within 16-row group
  const int skc = (sl & 3) * 8;                   // k-offset (bf16)
  // read geometry: logical slot (m-parity, kchunk=quad) -> swizzled slot
  const int rrow = mr >> 1;
  const int rcol = ((((mr & 1) << 2) | quad) ^ rrow) * 8;

  f32x4 acc[IW][JW] = {};

  // hoisted staging pointers: per-lane global src, per-lane LDS dst
  const size_t gK = (size_t)16 * K;
  const __bf16* aS = A + (size_t)(m0 + wid * (MT / 4) + srow2) * K + skc;
  const __bf16* bS = BT + (size_t)(n0 + wid * (NT / 4) + srow2) * K + skc;
  __bf16* dA0 = &As[0][wid * (MT / 8)][0] + lane * 8;  // linear: lane*16B
  __bf16* dB0 = &Bs[0][wid * (NT / 8)][0] + lane * 8;

  auto stage = [&](int k0, int buf) {
    __bf16* da = dA0 + buf * (MT * 32);
    __bf16* db = dB0 + buf * (NT * 32);
    for (int g = 0; g < MT / 64; g++) gl2lds16(aS + k0 + g * gK, da + g * 512);
    for (int g = 0; g < NT / 64; g++) gl2lds16(bS + k0 + g * gK, db + g * 512);
  };

  const int T = K / 32;
  for (int r = 0; r < RING - 1; r++) stage(r * 32, r);
  for (int it = 0; it < T; it++) {
    // drain stage(it); keep min(RING-2, T-1-it) newer stages in flight
    const int rem = T - 1 - it;
    if (rem >= RING - 2) {
      pipe_barrier<(RING - 2) * S>();
    } else if constexpr (RING == 4) {
      if (rem == 1) pipe_barrier<S>(); else pipe_barrier<0>();
    } else {
      pipe_barrier<0>();
    }
    if (it + RING - 1 < T) stage((it + RING - 1) * 32, (it + RING - 1) % RING);
    const int pb = it % RING;
    bf16x8 af[IW], bfr[JW];
    for (int i = 0; i < IW; i++)
      af[i] = *(bf16x8*)&As[pb][wr * (MT / 4) + i * 8 + rrow][rcol];
    for (int j = 0; j < JW; j++)
      bfr[j] = *(bf16x8*)&Bs[pb][wc * (NT / 4) + j * 8 + rrow][rcol];
    for (int i = 0; i < IW; i++)
      for (int j = 0; j < JW; j++)
        acc[i][j] = __builtin_amdgcn_mfma_f32_16x16x32_bf16(af[i], bfr[j], acc[i][j], 0, 0, 0);
  }

  float ga = 0.f, gb = 0.f, gc = 0.f;
  if (EPI == 1) { ga = *c0p; gb = *c1p; gc = *c2p; }

  for (int i = 0; i < IW; i++) {
    for (int j = 0; j < JW; j++) {
      int col = n0 + wc * (NT / 2) + j * 16 + mr;
      float bv = bias[col];
      int row0 = m0 + wr * (MT / 2) + i * 16 + quad * 4;
      if (EPI == 3 && col >= 1536) {
        // V-part: write directly into V^T[(b*12+h)*64+d][token], 4 tokens/lane
        int hh = (col >> 6) - 24, dd = col & 63;
        bf16x4 pk;
        for (int r = 0; r < 4; r++) pk[r] = (__bf16)(acc[i][j][r] + bv);
        *(bf16x4*)&vtb[(((size_t)(row0 >> 11) * 12 + hh) * 64 + dd) * 2048 +
                       (row0 & 2047)] = pk;
      } else {
        for (int r = 0; r < 4; r++) {
          size_t idx = (size_t)(row0 + r) * N + col;
          float c = acc[i][j][r] + bv;
          if (EPI == 1) {
            float u = (ga * c + gb) * c + gc;
            ((__bf16*)outv)[idx] = (__bf16)u;
          } else if (EPI == 2) {
            ((float*)outv)[idx] = c + res[idx];
          } else {
            ((__bf16*)outv)[idx] = (__bf16)c;
          }
        }
      }
    }
  }
}

// -------- flash-style polynomial attention --------
// grid(48, 16): x = b*12+h (same-head q-tiles share an XCD), y = q-tile.
// P kept fully in registers (cvt_pk + permlane, T12). Row-sum via
// ones-vector MFMA (pf as B-operand -> C[.][q=mr] = rowsum) (R8/R10+-verified).
// setprio kept here: independent per-block waves (phase-diverse) — T5 pays.
__global__ __launch_bounds__(256, 3) void attn_poly(const __bf16* __restrict__ qkv,
                                                    const __bf16* __restrict__ vt,
                                                    __bf16* __restrict__ outp,
                                                    const float* __restrict__ ap,
                                                    const float* __restrict__ bp,
                                                    const float* __restrict__ cp) {
  __shared__ __bf16 Kb[2][64][64];   // 16,384 B (unpadded, swizzled chunks)
  __shared__ __bf16 Vb[2][64][64];   // 16,384 B

  const int tid = threadIdx.x, lane = tid & 63, wid = tid >> 6;
  const int mr = lane & 15, quad = lane >> 4;
  const int bh = blockIdx.x;
  const int h = bh % 12, b = bh / 12;
  const int q0 = blockIdx.y * 128;
  const size_t baseQ = ((size_t)b * 2048) * 2304 + h * 64;

  const int swzsrc = (((lane & 7) ^ ((lane >> 3) & 7)) * 8);
  const int srow8 = lane >> 3;
  const int colS0 = ((quad ^ (mr & 7)) * 8);
  const int colS1 = (((4 + quad) ^ (mr & 7)) * 8);

  bf16x8 qf[2][2];
  for (int i = 0; i < 2; i++)
    for (int s = 0; s < 2; s++)
      qf[i][s] = *(const bf16x8*)&qkv[baseQ + (size_t)(q0 + wid * 32 + i * 16 + mr) * 2304 +
                                      s * 32 + quad * 8];

  const float a2 = (*ap) * 0.015625f, b2 = (*bp) * 0.125f, cc = *cp;
  f32x4 o_acc[2][4] = {};
  f32x4 osum[2] = {};                // MFMA row-sum accumulators
  const f32x4 z4 = {0.f, 0.f, 0.f, 0.f};  // persistent MFMA C-zero
  const bf16x8 ones = {(__bf16)1.f, (__bf16)1.f, (__bf16)1.f, (__bf16)1.f,
                       (__bf16)1.f, (__bf16)1.f, (__bf16)1.f, (__bf16)1.f};

  // staging pointers: per-lane global src advanced by constant strides
  const __bf16* kp = qkv + baseQ + 768 + (size_t)(wid * 16 + srow8) * 2304 + swzsrc;
  const __bf16* vp = vt + ((size_t)bh * 64 + wid * 16 + srow8) * 2048 + swzsrc;
  __bf16* kd0 = &Kb[0][wid * 16 + srow8][(lane & 7) * 8];
  __bf16* vd0 = &Vb[0][wid * 16 + srow8][(lane & 7) * 8];

  auto stage = [&](const __bf16* kpp, const __bf16* vpp, int pbuf) {
    __bf16* kd = kd0 + pbuf * 4096;
    __bf16* vd = vd0 + pbuf * 4096;
    gl2lds16(kpp, kd);
    gl2lds16(kpp + 8 * 2304, kd + 512);
    gl2lds16(vpp, vd);
    gl2lds16(vpp + 8 * 2048, vd + 512);
  };

  stage(kp, vp, 0);
  const __bf16* kpn = kp + 64 * 2304;
  const __bf16* vpn = vp + 64;
  int pb = 0;
  for (int kt = 0; kt < 32; kt++) {
    __syncthreads();
    if (kt < 31) { stage(kpn, vpn, pb ^ 1); kpn += 64 * 2304; vpn += 64; }
    const __bf16* kb = &Kb[pb][0][0];
    const __bf16* vb = &Vb[pb][0][0];

    // QK^T (swapped: A=K rows, B=Q rows) -> lane(mr,quad) holds
    // S[q=mr][k = j*16 + quad*4 + r] in sacc[i][j][r]
    f32x4 sacc[2][4];
    __builtin_amdgcn_s_setprio(1);
    for (int j = 0; j < 4; j++) {
      bf16x8 kf0 = *(bf16x8*)(kb + (j * 16 + mr) * 64 + colS0);
      bf16x8 kf1 = *(bf16x8*)(kb + (j * 16 + mr) * 64 + colS1);
      for (int i = 0; i < 2; i++) {
        sacc[i][j] = __builtin_amdgcn_mfma_f32_16x16x32_bf16(kf0, qf[i][0], z4, 0, 0, 0);
        sacc[i][j] = __builtin_amdgcn_mfma_f32_16x16x32_bf16(kf1, qf[i][1], sacc[i][j], 0, 0, 0);
      }
    }
    __builtin_amdgcn_s_setprio(0);

    // activation + in-register P redistribution into PV A-fragments:
    // target lane(mr,quad) needs P[q=mr][k = s*32 + quad*8 + e], e=0..7.
    bf16x8 pf[2][2];
    for (int i = 0; i < 2; i++) {
      unsigned w0[4], w1[4];
      for (int j = 0; j < 4; j++) {
        f32x4 S = sacc[i][j];
        f32x4 p = (a2 * S + b2) * S + cc;
        p[0] = fmaxf(p[0], 1e-6f); p[1] = fmaxf(p[1], 1e-6f);
        p[2] = fmaxf(p[2], 1e-6f); p[3] = fmaxf(p[3], 1e-6f);
        w0[j] = cvt_pk_bf16(p[0], p[1]);
        w1[j] = cvt_pk_bf16(p[2], p[3]);
      }
      for (int s = 0; s < 2; s++) {
        unsigned a0 = w0[2 * s], b0 = w0[2 * s + 1];
        unsigned a1 = w1[2 * s], b1 = w1[2 * s + 1];
        plane32_swap(a0, b0); plane16_swap(a0, b0);
        plane32_swap(a1, b1); plane16_swap(a1, b1);
        u32x4v t = {a0, a1, b0, b1};
        pf[i][s] = __builtin_bit_cast(bf16x8, t);
      }
    }

    // PV: o[q][d] += P[q][k] * V^T[d][k] ; row-sum via ones-MFMA
    __builtin_amdgcn_s_setprio(1);
    for (int s = 0; s < 2; s++) {
      for (int i = 0; i < 2; i++)
        osum[i] = __builtin_amdgcn_mfma_f32_16x16x32_bf16(ones, pf[i][s], osum[i], 0, 0, 0);
      for (int dt = 0; dt < 4; dt++) {
        bf16x8 vf = *(bf16x8*)(vb + (dt * 16 + mr) * 64 + (s ? colS1 : colS0));
        for (int i = 0; i < 2; i++)
          o_acc[i][dt] = __builtin_amdgcn_mfma_f32_16x16x32_bf16(pf[i][s], vf, o_acc[i][dt], 0, 0, 0);
      }
    }
    __builtin_amdgcn_s_setprio(0);
    pb ^= 1;
  }

  size_t baseO = ((size_t)b * 2048) * 768 + h * 64;
  for (int i = 0; i < 2; i++) {
    float l_acc = osum[i][0];  // rowsum(q=mr), replicated across regs
    float inv[4];
    for (int r = 0; r < 4; r++)
      inv[r] = 1.0f / (__shfl(l_acc, quad * 4 + r, 64) + 1e-8f);
    for (int dt = 0; dt < 4; dt++) {
      int q = q0 + wid * 32 + i * 16 + quad * 4;
      for (int r = 0; r < 4; r++)
        outp[baseO + (size_t)(q + r) * 768 + dt * 16 + mr] =
            (__bf16)(o_acc[i][dt][r] * inv[r]);
    }
  }
}

extern "C" void kernel_launch(void* const* d_in, const int* in_sizes, int n_in,
                              void* d_out, int out_size, void* d_ws, size_t ws_size,
                              hipStream_t stream) {
  const float* x     = (const float*)d_in[0];
  const float* ln1g  = (const float*)d_in[1];
  const float* ln1b  = (const float*)d_in[2];
  const float* ln2g  = (const float*)d_in[3];
  const float* ln2b  = (const float*)d_in[4];
  const float* qkvw  = (const float*)d_in[5];
  const float* qkvb  = (const float*)d_in[6];
  const float* projw = (const float*)d_in[7];
  const float* projb = (const float*)d_in[8];
  const float* fc1w  = (const float*)d_in[9];
  const float* fc1b  = (const float*)d_in[10];
  const float* fc2w  = (const float*)d_in[11];
  const float* fc2b  = (const float*)d_in[12];
  const float* attna = (const float*)d_in[13];
  const float* attnb = (const float*)d_in[14];
  const float* attnc = (const float*)d_in[15];
  const float* gelua = (const float*)d_in[16];
  const float* gelub = (const float*)d_in[17];
  const float* geluc = (const float*)d_in[18];

  char* ws = (char*)d_ws;
  __bf16* wT_qkv  = (__bf16*)(ws);             // [2304][768]  3,538,944 B
  __bf16* wT_proj = (__bf16*)(ws + 3538944);   // [768][768]   1,179,648 B
  __bf16* wT_fc1  = (__bf16*)(ws + 4718592);   // [3072][768]  4,718,592 B
  __bf16* wT_fc2  = (__bf16*)(ws + 9437184);   // [768][3072]  4,718,592 B
  __bf16* h       = (__bf16*)(ws + 14155776);  // [8192][768]  bf16 12,582,912 B
  float*  x1      = (float*)(ws + 26738688);   // [8192][768]  f32  25,165,824 B
  __bf16* qkvbuf  = (__bf16*)(ws + 51904512);  // [8192][2304] bf16 (dead after attn)
  __bf16* u       = (__bf16*)(ws + 51904512);  // [8192][3072] bf16 (overlaps qkv)
  __bf16* vtbuf   = (__bf16*)(ws + 89653248);  // [3072][2048] bf16 (live qkv->attn only)
  float*  outp    = (float*)d_out;

  // all 4 weight transposes in one dispatch (6912 tiles)
  transpose_all<<<6912, 256, 0, stream>>>(qkvw, wT_qkv, projw, wT_proj,
                                          fc1w, wT_fc1, fc2w, wT_fc2);

  ln_kernel<<<8192, 256, 0, stream>>>(x, ln1g, ln1b, h);
  // qkv GEMM with fused V^T epilogue (writes Q|K to qkvbuf, V^T to vtbuf)
  gemm_pl<128, 128, 3, false, 3, 3><<<dim3(18, 64), 256, 0, stream>>>(
      h, wT_qkv, qkvb, nullptr, qkvbuf, vtbuf, 8192, 2304, 768, nullptr, nullptr, nullptr);
  // grid: x = b*12+h (XCD-local K/V reuse), y = q-tile
  attn_poly<<<dim3(48, 16), 256, 0, stream>>>(qkvbuf, vtbuf, h, attna, attnb, attnc);
  // proj (+x residual) -> x1 f32 ; 64x128, RING=4 (settled thin-GEMM optimum)
  gemm_pl<64, 128, 2, true, 3, 4><<<dim3(128, 6), 256, 0, stream>>>(
      h, wT_proj, projb, x, x1, nullptr, 8192, 768, 768, nullptr, nullptr, nullptr);
  ln_kernel<<<8192, 256, 0, stream>>>(x1, ln2g, ln2b, h);
  // fc1 + gelu: 128x128 (R7-proven), RING=3
  gemm_pl<128, 128, 1, false, 3, 3><<<dim3(24, 64), 256, 0, stream>>>(
      h, wT_fc1, fc1b, nullptr, u, nullptr, 8192, 3072, 768, gelua, gelub, geluc);
  // fc2 (+x1 residual) -> out f32 ; 64x128, RING=4 (R11: 73.2 -> 70.7 us)
  gemm_pl<64, 128, 2, true, 3, 4><<<dim3(128, 6), 256, 0, stream>>>(
      u, wT_fc2, fc2b, x1, outp, nullptr, 8192, 768, 3072, nullptr, nullptr, nullptr);
}